// Round 7
// baseline (670.917 us; speedup 1.0000x reference)
//
#include <hip/hip_runtime.h>
#include <hip/hip_bf16.h>

typedef unsigned short u16;
typedef unsigned long long u64;
typedef __attribute__((ext_vector_type(8))) short  bf16x8;
typedef __attribute__((ext_vector_type(4))) short  bf16x4;
typedef __attribute__((ext_vector_type(4))) float  f32x4;
typedef __attribute__((ext_vector_type(4))) int    i32x4;
typedef __attribute__((ext_vector_type(4))) float  f32x4v;

#define MFMA16(a,b,c) __builtin_amdgcn_mfma_f32_16x16x32_bf16((a),(b),(c),0,0,0)
#define EXP2(x) __builtin_amdgcn_exp2f(x)

#if defined(__has_builtin)
#if __has_builtin(__builtin_amdgcn_mfma_f32_16x16x16bf16_1k)
#define HAVE_MFMA_16X16X16_BF16 1
#endif
#endif

// B=4, S=1024, D=1024, H=16, HD=64
// qkv layout: [4096 rows][2048 cols] bf16 (q|k); V goes straight to vt
// vt layout:  [b][h][hd(64)][s(1024)] bf16
// mixed:      [b][g][s][t] bf16, stores 0.5*log2e*(Wc@prev + bc)

static constexpr size_t OFF_HBF = 0;                  // 4096*1024*2 = 8388608
static constexpr size_t OFF_WBF = 8388608;            // 3072*1024*2 = 6291456
static constexpr size_t OFF_QKV = 14680064;           // 4096*2048*2 = 16777216
static constexpr size_t OFF_VT  = 31457280;           // 4*16*64*1024*2 = 8388608
static constexpr size_t OFF_MIX = 39845888;           // 4*16*1024*1024*2 = 134217728

static constexpr float LOG2E  = 1.44269504088896340736f;
static constexpr float SSCALE = 0.125f * LOG2E;       // QK^T scale * log2e
static constexpr float HALF2E = 0.5f * LOG2E;         // blend weight * log2e

__device__ __forceinline__ u16 f2b(float f) {
  unsigned int u = __builtin_bit_cast(unsigned int, f);
  unsigned int r = (u + 0x7fffu + ((u >> 16) & 1u)) >> 16;
  return (u16)r;
}
__device__ __forceinline__ float b2f(u16 x) {
  union { unsigned int u; float f; } c; c.u = ((unsigned int)x) << 16; return c.f;
}

__device__ __forceinline__ void gload_lds16(const u16* g, u16* l) {
  __builtin_amdgcn_global_load_lds(
      (const __attribute__((address_space(1))) unsigned int*)g,
      (__attribute__((address_space(3))) unsigned int*)l, 16, 0, 0);
}

// 16x16x16 bf16 MFMA. Prefer the builtin (compiler owns hazards); fall back to
// inline asm with manual s_nop guards (gfx950 unified VGPR file: v[] ok).
__device__ __forceinline__ f32x4 pv_mfma(bf16x4 a, bf16x4 b, f32x4 c) {
#ifdef HAVE_MFMA_16X16X16_BF16
  return __builtin_amdgcn_mfma_f32_16x16x16bf16_1k(a, b, c, 0, 0, 0);
#else
  asm("s_nop 1\n\tv_mfma_f32_16x16x16_bf16 %0, %1, %2, %0"
      : "+v"(c) : "v"(a), "v"(b));
  return c;
#endif
}

// ---------------- kernel 1: fp32 -> bf16 convert -------------------------------
__global__ void __launch_bounds__(256) k_convert(
    const float* __restrict__ hid, const float* __restrict__ wq,
    const float* __restrict__ wk,  const float* __restrict__ wv,
    u16* __restrict__ hbf, u16* __restrict__ wbf)
{
  int i4 = blockIdx.x * 256 + threadIdx.x;
  f32x4v v; u16* dst;
  if (i4 < 1048576) {
    v = *(const f32x4v*)(hid + (size_t)i4 * 4);
    dst = hbf + (size_t)i4 * 4;
  } else {
    int j = (i4 - 1048576) * 4;
    const float* s = (j < 1048576) ? (wq + j)
                   : (j < 2097152) ? (wk + (j - 1048576))
                                   : (wv + (j - 2097152));
    v = *(const f32x4v*)s;
    dst = wbf + j;
  }
  u16 o[4];
  for (int k = 0; k < 4; ++k) o[k] = f2b(v[k]);
  *(u64*)dst = *(u64*)o;
}

// ---------------- kernel 2: fused QKV GEMM; V written transposed ---------------
__global__ void __launch_bounds__(256) k_qkv(
    const u16* __restrict__ Abf, const u16* __restrict__ Wbf,
    const float* __restrict__ bq, const float* __restrict__ bk,
    const float* __restrict__ bv, u16* __restrict__ qkv, u16* __restrict__ vt)
{
  __shared__ __align__(16) u16 As[2][128][32];
  __shared__ __align__(16) u16 Bs[2][128][32];
  const int n0 = blockIdx.x * 128;
  const int m0 = blockIdx.y * 128;
  const int tid = threadIdx.x;
  const int l = tid & 63, w = tid >> 6;
  const int lr = l & 15, lg = l >> 4;
  const int wm = (w >> 1) * 64, wn = (w & 1) * 64;
  const int sx = (lg ^ ((lr >> 1) & 3)) * 8;

  f32x4 acc[4][4] = {};

  auto issue = [&](int buf, int k0) {
#pragma unroll
    for (int i = 0; i < 2; ++i) {
      int c = tid + i * 256;
      int row = c >> 2, cc = c & 3;
      int gc = cc ^ ((row >> 1) & 3);
      gload_lds16(Abf + (size_t)(m0 + row) * 1024 + k0 + gc * 8, &As[buf][row][cc * 8]);
      gload_lds16(Wbf + (size_t)(n0 + row) * 1024 + k0 + gc * 8, &Bs[buf][row][cc * 8]);
    }
  };

  issue(0, 0);
  for (int k0 = 0; k0 < 1024; k0 += 32) {
    int kb = (k0 >> 5) & 1;
    __syncthreads();
    if (k0 + 32 < 1024) issue(kb ^ 1, k0 + 32);
    bf16x8 a[4], bb[4];
#pragma unroll
    for (int mi = 0; mi < 4; ++mi)
      a[mi] = *(const bf16x8*)(&As[kb][wm + mi * 16 + lr][sx]);
#pragma unroll
    for (int ni = 0; ni < 4; ++ni)
      bb[ni] = *(const bf16x8*)(&Bs[kb][wn + ni * 16 + lr][sx]);
#pragma unroll
    for (int mi = 0; mi < 4; ++mi)
#pragma unroll
      for (int ni = 0; ni < 4; ++ni)
        acc[mi][ni] = MFMA16(a[mi], bb[ni], acc[mi][ni]);
  }
#pragma unroll
  for (int mi = 0; mi < 4; ++mi)
#pragma unroll
    for (int ni = 0; ni < 4; ++ni) {
      int col = n0 + wn + ni * 16 + lr;
      const float* bias = (col < 1024) ? bq : (col < 2048) ? bk : bv;
      float bvv = bias[col & 1023];
      int rowb = m0 + wm + mi * 16 + lg * 4;
      if (col < 2048) {
#pragma unroll
        for (int r = 0; r < 4; ++r)
          qkv[(size_t)(rowb + r) * 2048 + col] = f2b(acc[mi][ni][r] + bvv);
      } else {
        int hh = (col >> 6) & 15, d = col & 63;
        int bb2 = rowb >> 10, sl = rowb & 1023;
        u16 o[4];
#pragma unroll
        for (int r = 0; r < 4; ++r) o[r] = f2b(acc[mi][ni][r] + bvv);
        *(u64*)(vt + ((size_t)(bb2 * 16 + hh) * 64 + d) * 1024 + sl) = *(u64*)o;
      }
    }
}

// ---------------- kernel 3: head-mix, stores 0.5*log2e*(Wc@prev+bc) ------------
__global__ void __launch_bounds__(256) k_mix(
    const float* __restrict__ prev, const float* __restrict__ Wc,
    const float* __restrict__ bc, u16* __restrict__ mixed)
{
  __shared__ float wcs[256];
  __shared__ float bcs[16];
  int bsi = blockIdx.x;                 // 4096 = b*1024+s
  int b = bsi >> 10, s = bsi & 1023;
  int tid = threadIdx.x;
  wcs[tid] = HALF2E * Wc[tid];
  if (tid < 16) bcs[tid] = HALF2E * bc[tid];
  __syncthreads();
  size_t base = (size_t)b * 16777216 + (size_t)s * 1024;
  int t = tid * 4;
  f32x4v p[16];
#pragma unroll
  for (int hh = 0; hh < 16; ++hh)
    p[hh] = *(const f32x4v*)(prev + base + (size_t)hh * 1048576 + t);
#pragma unroll
  for (int g = 0; g < 16; ++g) {
    float bg = bcs[g];
    f32x4v a = {bg, bg, bg, bg};
#pragma unroll
    for (int hh = 0; hh < 16; ++hh)
      a += p[hh] * wcs[g * 16 + hh];
    u16 o[4];
#pragma unroll
    for (int j = 0; j < 4; ++j) o[j] = f2b(a[j]);
    *(u64*)(mixed + base + (size_t)g * 1048576 + t) = *(u64*)o;
  }
}

// ---------------- kernel 4: fused attention, swapped-QK^T streaming ------------
// block = (b, h, 16 s-rows); 4 waves split t (256 each). No score LDS at all.
// S' = K·Q^T: lane holds S'[t=lg*4+r][s=ls] -> exactly the B-frag of the
// 16x16x16 PV MFMA (ctx^T = V^T · P'). Pass 1 caches exp2(sv) as bf16 in regs.
__global__ void __launch_bounds__(256, 4) k_attn(
    const u16* __restrict__ qkv, const u16* __restrict__ vt,
    const u16* __restrict__ mixed, const float* __restrict__ mask,
    float* __restrict__ out)
{
  __shared__ float ctxw[4][16][68];     // padded: 2-way bank alias only
  __shared__ float lw1[4][16], lw2[4][16];

  int blk = blockIdx.x;                 // 4096 = ((b*16+h)*64 + sb)
  int sb = blk & 63, bh = blk >> 6;
  int h = bh & 15, b = bh >> 4;
  int s0 = sb * 16;
  int tid = threadIdx.x;
  int l = tid & 63, w = tid >> 6;
  int ls = l & 15, lg = l >> 4;
  const int tw = w * 256;

  // Q fragment (B-operand of S'=K·Q^T): lane: s=ls, d=lg*8+i
  const size_t qrow = (size_t)(b * 1024 + s0 + ls) * 2048 + h * 64;
  bf16x8 bq0 = *(const bf16x8*)(qkv + qrow + lg * 8);
  bf16x8 bq1 = *(const bf16x8*)(qkv + qrow + 32 + lg * 8);

  const size_t kbase = (size_t)b * 1024 * 2048 + 1024 + h * 64;

  // ---- pass 1: softmax-1 denominator; cache exp2(sv) as bf16 in regs ----
  float sum1 = 0.f;
  bf16x4 pst[16];
#pragma unroll
  for (int it = 0; it < 16; ++it) {
    int t0 = tw + it * 16;
    const u16* kr = qkv + kbase + (size_t)(t0 + ls) * 2048;
    bf16x8 ak0 = *(const bf16x8*)(kr + lg * 8);        // A: K[t=t0+ls][d]
    bf16x8 ak1 = *(const bf16x8*)(kr + 32 + lg * 8);
    f32x4 acc = {0.f, 0.f, 0.f, 0.f};
    acc = MFMA16(ak0, bq0, acc);                       // S'[t][s]
    acc = MFMA16(ak1, bq1, acc);
    f32x4v mk4 = *(const f32x4v*)(mask + b * 1024 + t0 + lg * 4);
#pragma unroll
    for (int r = 0; r < 4; ++r) {
      float p = EXP2(acc[r] * SSCALE + mk4[r] * LOG2E);
      sum1 += p;
      pst[it][r] = (short)f2b(p);
    }
  }
  sum1 += __shfl_xor(sum1, 16);
  sum1 += __shfl_xor(sum1, 32);
  if (lg == 0) lw1[w][ls] = sum1;
  __syncthreads();
  float l1h = HALF2E / (lw1[0][ls] + lw1[1][ls] + lw1[2][ls] + lw1[3][ls]);

  // ---- pass 2: blend + exp2 + PV (ctx^T accumulate), no recompute ----
  float den = 0.f;
  f32x4 cacc[4] = {};
  const size_t mixrow = ((size_t)(b * 16 + h) * 1024 + s0 + ls) * 1024;
  const size_t vbase = (size_t)(b * 16 + h) * 65536;
#pragma unroll
  for (int it = 0; it < 16; ++it) {
    int t0 = tw + it * 16;
    u64 mxw = *(const u64*)(mixed + mixrow + t0 + lg * 4);
    const u16* mxp = (const u16*)&mxw;
    bf16x4 pa;
#pragma unroll
    for (int r = 0; r < 4; ++r) {
      float bl = fmaf(b2f((u16)pst[it][r]), l1h, b2f(mxp[r]));
      float p = EXP2(bl);
      den += p;
      pa[r] = (short)f2b(p);
    }
#pragma unroll
    for (int j = 0; j < 4; ++j) {
      bf16x4 va = *(const bf16x4*)(vt + vbase +
                    (size_t)(j * 16 + ls) * 1024 + t0 + lg * 4);
      cacc[j] = pv_mfma(va, pa, cacc[j]);   // ctx^T[d=j*16+lg*4+r][s=ls]
    }
  }
  den += __shfl_xor(den, 16);
  den += __shfl_xor(den, 32);
#ifndef HAVE_MFMA_16X16X16_BF16
  asm volatile("s_nop 7\n\ts_nop 7\n\ts_nop 7");   // MFMA->VALU/LDS read hazard
#endif
  if (lg == 0) lw2[w][ls] = den;
#pragma unroll
  for (int j = 0; j < 4; ++j)
    *(f32x4*)(&ctxw[w][ls][j * 16 + lg * 4]) = cacc[j];
  __syncthreads();

  // ---- merge 4 wave partials + normalize + store ----
  {
    int row = tid >> 4, d4 = (tid & 15) * 4;
    float inv = 1.0f / (lw2[0][row] + lw2[1][row] + lw2[2][row] + lw2[3][row]);
    f32x4 a0 = *(const f32x4*)(&ctxw[0][row][d4]);
    f32x4 a1 = *(const f32x4*)(&ctxw[1][row][d4]);
    f32x4 a2 = *(const f32x4*)(&ctxw[2][row][d4]);
    f32x4 a3 = *(const f32x4*)(&ctxw[3][row][d4]);
    f32x4 o = (a0 + a1 + a2 + a3) * inv;
    *(f32x4*)(out + ((size_t)(b * 1024 + s0 + row)) * 1024 + h * 64 + d4) = o;
  }
}

// ---------------- launcher ------------------------------------------------------
extern "C" void kernel_launch(void* const* d_in, const int* in_sizes, int n_in,
                              void* d_out, int out_size, void* d_ws, size_t ws_size,
                              hipStream_t stream) {
  const float* hidden = (const float*)d_in[0];
  const float* mask   = (const float*)d_in[1];
  const float* prev   = (const float*)d_in[2];
  const float* Wq     = (const float*)d_in[3];
  const float* bq     = (const float*)d_in[4];
  const float* Wk     = (const float*)d_in[5];
  const float* bk     = (const float*)d_in[6];
  const float* Wv     = (const float*)d_in[7];
  const float* bv     = (const float*)d_in[8];
  const float* Wc     = (const float*)d_in[9];
  const float* bc     = (const float*)d_in[10];
  float* out = (float*)d_out;
  char* ws = (char*)d_ws;

  u16* hbf   = (u16*)(ws + OFF_HBF);
  u16* wbf   = (u16*)(ws + OFF_WBF);
  u16* qkv   = (u16*)(ws + OFF_QKV);
  u16* vt    = (u16*)(ws + OFF_VT);
  u16* mixed = (u16*)(ws + OFF_MIX);

  k_convert<<<7168, 256, 0, stream>>>(hidden, Wq, Wk, Wv, hbf, wbf);
  k_qkv<<<dim3(24, 32), 256, 0, stream>>>(hbf, wbf, bq, bk, bv, qkv, vt);
  k_mix<<<4096, 256, 0, stream>>>(prev, Wc, bc, mixed);
  k_attn<<<4096, 256, 0, stream>>>(qkv, vt, mixed, mask, out);
}